// Round 6
// baseline (384.853 us; speedup 1.0000x reference)
//
#include <hip/hip_runtime.h>
#include <hip/hip_cooperative_groups.h>

namespace coop = cooperative_groups;

typedef float f32x4 __attribute__((ext_vector_type(4)));

// Problem shape (fixed by setup_inputs): B=64, C=1024, H*W=1024, M=768.
#define NB 64
#define NC 1024
#define HW 1024
#define HW4 256          // HW / 4
#define CCH 16           // channel groups; grid = CCH*NB = 1024 blocks
#define CPC (NC / CCH)   // 64 channels per group

// Fused three-phase kernel (cooperative). Block bid -> (cg = bid>>6, b = bid&63).
// Phase 1: GEMV  partial[cg][b][hw] = sum_{c in group} fm[b,c,hw]*w[c]
// Phase 2: (blocks with cg<4) reduce partials -> logit, sigmoid -> attn out,
//          exact top-M rank mask (logit ranking; sigmoid strictly monotone).
// Phase 3: out = fm * mask (mask loop-invariant per thread, NT load/store).
__global__ void __launch_bounds__(256, 4)
adl_fused(const float* __restrict__ fm,
          const float* __restrict__ w,
          const float* __restrict__ conv_b,
          const int* __restrict__ Mptr,
          float* __restrict__ out,
          float* __restrict__ attn_out,
          float* __restrict__ partial,
          float* __restrict__ mask) {
    const int bid = blockIdx.x;
    const int b   = bid & (NB - 1);
    const int cg  = bid >> 6;
    const int t   = threadIdx.x;             // 0..255 == hw4 in phases 1,3

    __shared__ float wsh[CPC];
    __shared__ f32x4 s_sh4[HW4];
    float* s_sh = (float*)s_sh4;

    // ---- phase 1: GEMV ----
    if (t < CPC) wsh[t] = w[cg * CPC + t];
    __syncthreads();
    {
        const f32x4* fm4 = (const f32x4*)fm;
        size_t base = ((size_t)(b * NC + cg * CPC)) * HW4 + t;
        f32x4 acc = {0.f, 0.f, 0.f, 0.f};
        #pragma unroll 8
        for (int ci = 0; ci < CPC; ++ci) {
            acc += fm4[base] * wsh[ci];
            base += HW4;
        }
        ((f32x4*)partial)[((size_t)(cg * NB + b)) * HW4 + t] = acc;
    }
    coop::this_grid().sync();

    // ---- phase 2: topk mask (256 of 1024 blocks) ----
    if (cg < 4) {
        const int slice = cg;
        const float bias = conv_b[0];
        #pragma unroll
        for (int q = 0; q < 4; ++q) {
            const int tt = q * 256 + t;
            float s = bias;
            #pragma unroll 8
            for (int k = 0; k < CCH; ++k)
                s += partial[((size_t)(k * NB + b)) * HW + tt];
            s_sh[tt] = s;
        }
        __syncthreads();
        const int tt = slice * 256 + t;
        const float sv = s_sh[tt];
        const int M = *Mptr;
        int r = 0;
        #pragma unroll 4
        for (int j4 = 0; j4 < HW4; ++j4) {
            const f32x4 v = s_sh4[j4];       // broadcast LDS read
            const int j = j4 * 4;
            r += (v.x > sv) || (v.x == sv && (j + 0) < tt);
            r += (v.y > sv) || (v.y == sv && (j + 1) < tt);
            r += (v.z > sv) || (v.z == sv && (j + 2) < tt);
            r += (v.w > sv) || (v.w == sv && (j + 3) < tt);
        }
        attn_out[(size_t)b * HW + tt] = 1.0f / (1.0f + expf(-sv));
        mask[(size_t)b * HW + tt] = (r < M) ? 0.0f : 1.0f;
    }
    coop::this_grid().sync();

    // ---- phase 3: apply ----
    {
        const f32x4* fm4   = (const f32x4*)fm;
        const f32x4* mask4 = (const f32x4*)mask;
        f32x4* out4        = (f32x4*)out;
        const f32x4 m = mask4[b * HW4 + t];
        size_t base = ((size_t)(b * NC + cg * CPC)) * HW4 + t;
        #pragma unroll 4
        for (int ci = 0; ci < CPC; ++ci) {
            const f32x4 v = __builtin_nontemporal_load(&fm4[base]);
            __builtin_nontemporal_store(v * m, &out4[base]);
            base += HW4;
        }
    }
}

// ---- round-4 fallback kernels (used only if cooperative launch fails) ----
__global__ void __launch_bounds__(256)
adl_gemv(const float* __restrict__ fm, const float* __restrict__ w,
         float* __restrict__ partial) {
    const int cg = blockIdx.x, b = blockIdx.y, t = threadIdx.x;
    const f32x4* fm4 = (const f32x4*)fm;
    const int cbase = cg * CPC;
    size_t base = ((size_t)(b * NC + cbase)) * HW4 + t;
    f32x4 acc = {0.f, 0.f, 0.f, 0.f};
    #pragma unroll 8
    for (int ci = 0; ci < CPC; ++ci) { acc += fm4[base] * w[cbase + ci]; base += HW4; }
    ((f32x4*)partial)[((size_t)(cg * NB + b)) * HW4 + t] = acc;
}

__global__ void __launch_bounds__(256)
adl_topk_mask(const float* __restrict__ partial, const float* __restrict__ conv_b,
              const int* __restrict__ Mptr, float* __restrict__ attn_out,
              float* __restrict__ mask) {
    __shared__ f32x4 s_sh4[HW4];
    float* s_sh = (float*)s_sh4;
    const int slice = blockIdx.x, b = blockIdx.y, tid = threadIdx.x;
    const float bias = conv_b[0];
    #pragma unroll
    for (int q = 0; q < 4; ++q) {
        const int t = q * 256 + tid;
        float s = bias;
        #pragma unroll 8
        for (int k = 0; k < CCH; ++k) s += partial[((size_t)(k * NB + b)) * HW + t];
        s_sh[t] = s;
    }
    __syncthreads();
    const int t = slice * 256 + tid;
    const float sv = s_sh[t];
    const int M = *Mptr;
    int r = 0;
    #pragma unroll 4
    for (int j4 = 0; j4 < HW4; ++j4) {
        const f32x4 v = s_sh4[j4];
        const int j = j4 * 4;
        r += (v.x > sv) || (v.x == sv && (j + 0) < t);
        r += (v.y > sv) || (v.y == sv && (j + 1) < t);
        r += (v.z > sv) || (v.z == sv && (j + 2) < t);
        r += (v.w > sv) || (v.w == sv && (j + 3) < t);
    }
    attn_out[(size_t)b * HW + t] = 1.0f / (1.0f + expf(-sv));
    mask[(size_t)b * HW + t] = (r < M) ? 0.0f : 1.0f;
}

__global__ void __launch_bounds__(256)
adl_apply(const float* __restrict__ fm, const float* __restrict__ mask,
          float* __restrict__ out) {
    const int cg = blockIdx.x, b = blockIdx.y, t = threadIdx.x;
    const f32x4* fm4 = (const f32x4*)fm;
    const f32x4* mask4 = (const f32x4*)mask;
    f32x4* out4 = (f32x4*)out;
    const f32x4 m = mask4[b * HW4 + t];
    size_t base = ((size_t)(b * NC + cg * CPC)) * HW4 + t;
    #pragma unroll 4
    for (int ci = 0; ci < CPC; ++ci) {
        const f32x4 v = __builtin_nontemporal_load(&fm4[base]);
        __builtin_nontemporal_store(v * m, &out4[base]);
        base += HW4;
    }
}

extern "C" void kernel_launch(void* const* d_in, const int* in_sizes, int n_in,
                              void* d_out, int out_size, void* d_ws, size_t ws_size,
                              hipStream_t stream) {
    const float* fm   = (const float*)d_in[0];   // [64,1024,32,32] f32
    const float* w    = (const float*)d_in[1];   // [1024] f32
    const float* bias = (const float*)d_in[2];   // [1] f32
    const int*   Mptr = (const int*)d_in[3];     // scalar int (768)

    float* out      = (float*)d_out;                       // dropped [B,C,H,W]
    float* attn_out = out + (size_t)NB * NC * HW;          // attn [B,1,H,W]

    // Workspace: partial [CCH][NB][HW] f32 (4 MB) + mask [NB][HW] f32 (256 KB).
    float* partial = (float*)d_ws;
    float* mask    = partial + (size_t)CCH * NB * HW;

    void* args[] = {(void*)&fm, (void*)&w, (void*)&bias, (void*)&Mptr,
                    (void*)&out, (void*)&attn_out, (void*)&partial, (void*)&mask};
    hipError_t err = hipLaunchCooperativeKernel((const void*)adl_fused,
                                                dim3(CCH * NB), dim3(256),
                                                args, 0, stream);
    if (err != hipSuccess) {
        // Fallback: proven 3-kernel path (round 4, 161 us).
        adl_gemv<<<dim3(CCH, NB), 256, 0, stream>>>(fm, w, partial);
        adl_topk_mask<<<dim3(4, NB), 256, 0, stream>>>(partial, bias, Mptr, attn_out, mask);
        adl_apply<<<dim3(CCH, NB), 256, 0, stream>>>(fm, mask, out);
    }
}